// Round 3
// baseline (702.524 us; speedup 1.0000x reference)
//
#include <hip/hip_runtime.h>
#include <hip/hip_bf16.h>

// Problem constants
#define B_N   4
#define CIN_  256
#define HH_   56
#define WW_   56
#define COUT_ 256
#define KK_   9
#define HW_   3136            // 56*56
#define NOFF  (B_N*18*HW_)    // offset conv outputs: 225792
#define NPOS  (B_N*KK_*HW_)   // bilinear entries: 112896

// ---------------------------------------------------------------------------
// Kernel 1: offset-predicting 3x3 conv (stride 1, pad 1), fp32.
// grid = B*18*H blocks of 64 threads (lane = w, 56 active).
// ---------------------------------------------------------------------------
__global__ __launch_bounds__(64) void k_offset(const float* __restrict__ x,
                                               const float* __restrict__ ow,
                                               const float* __restrict__ ob,
                                               float* __restrict__ offs) {
    int blk = blockIdx.x;
    int h = blk % HH_; int t = blk / HH_;
    int c = t % 18;    int b = t / 18;
    int w = threadIdx.x;
    if (w >= WW_) return;
    float acc = ob[c];
    for (int ci = 0; ci < CIN_; ++ci) {
        const float* xb = x + (size_t)((b*CIN_ + ci)*HH_)*WW_;
        const float* wb = ow + (size_t)(c*CIN_ + ci)*9;
        #pragma unroll
        for (int kh = 0; kh < 3; ++kh) {
            int yy = h + kh - 1;
            if (yy < 0 || yy >= HH_) continue;
            const float* xr = xb + yy*WW_;
            #pragma unroll
            for (int kw = 0; kw < 3; ++kw) {
                int xx = w + kw - 1;
                if (xx < 0 || xx >= WW_) continue;
                acc += xr[xx] * wb[kh*3 + kw];
            }
        }
    }
    offs[(size_t)(b*18 + c)*HW_ + h*WW_ + w] = acc;
}

// ---------------------------------------------------------------------------
// Kernel 2: transpose weight [Cout,Cin,3,3] -> Wt[kk][ci][o] (all fp32)
// so GEMM A-tile staging reads are contiguous in o.
// ---------------------------------------------------------------------------
__global__ __launch_bounds__(256) void k_wt(const float* __restrict__ wgt,
                                            float* __restrict__ Wt) {
    int i = blockIdx.x*256 + threadIdx.x;          // i = (kk*CIN + ci)*COUT + o
    if (i >= COUT_*CIN_*KK_) return;
    int o  = i % COUT_; int t = i / COUT_;
    int ci = t % CIN_;  int kk = t / CIN_;
    Wt[i] = wgt[(size_t)(o*CIN_ + ci)*KK_ + kk];
}

// ---------------------------------------------------------------------------
// Kernel 3: bilinear sampling params. For each (b, kk, pos): 4 corner flat
// indices (clamped) + 4 weights (0 if corner OOB) — matches reference's
// clip + validity-mask semantics exactly.
// ---------------------------------------------------------------------------
__global__ __launch_bounds__(256) void k_bilin(const float* __restrict__ offs,
                                               int4* __restrict__ pidx,
                                               float4* __restrict__ pwgt) {
    int i = blockIdx.x*256 + threadIdx.x;
    if (i >= NPOS) return;
    int pos = i % HW_; int t = i / HW_;
    int kk = t % KK_;  int b = t / KK_;
    int h = pos / WW_, w = pos % WW_;
    float dy = offs[(size_t)(b*18 + 2*kk    )*HW_ + pos];
    float dx = offs[(size_t)(b*18 + 2*kk + 1)*HW_ + pos];
    float py = (float)(h - 1 + kk/3) + dy;
    float px = (float)(w - 1 + kk%3) + dx;
    float y0f = floorf(py), x0f = floorf(px);
    int y0 = (int)y0f, x0 = (int)x0f;
    float ty = py - y0f, tx = px - x0f;
    int   ys[2] = {y0, y0 + 1},     xs[2] = {x0, x0 + 1};
    float wy[2] = {1.f - ty, ty},   wx[2] = {1.f - tx, tx};
    int idx[4]; float wt[4];
    #pragma unroll
    for (int jy = 0; jy < 2; ++jy) {
        #pragma unroll
        for (int jx = 0; jx < 2; ++jx) {
            int j = jy*2 + jx;
            int yy = ys[jy], xx = xs[jx];
            bool v = (yy >= 0) && (yy < HH_) && (xx >= 0) && (xx < WW_);
            int yc = min(max(yy, 0), HH_ - 1);
            int xc = min(max(xx, 0), WW_ - 1);
            idx[j] = yc*WW_ + xc;
            wt[j]  = v ? wy[jy]*wx[jx] : 0.f;
        }
    }
    pidx[i] = make_int4(idx[0], idx[1], idx[2], idx[3]);
    pwgt[i] = make_float4(wt[0], wt[1], wt[2], wt[3]);
}

// ---------------------------------------------------------------------------
// Kernel 4: main implicit GEMM (fp32 VALU this round).
// Block = 256 threads; tile = 256 cout x 32 positions; K-chunks of 32 cin,
// kk outer. Each thread: 8 cout x 4 pos accumulators.
// LDS: sA 32x256 f32 (32KB), sB 32x36 f32 (4.5KB), bilin params 1KB.
// ---------------------------------------------------------------------------
#define PTILE 32
#define CB    32
__global__ __launch_bounds__(256) void k_main(const float* __restrict__ x,
                                              const float* __restrict__ Wt,
                                              const int4* __restrict__ pidx,
                                              const float4* __restrict__ pwgt,
                                              float* __restrict__ out) {
    __shared__ float  sA[CB][COUT_];       // [cin_local][cout]
    __shared__ float  sB[CB][PTILE + 4];   // [cin_local][pos], stride 36
    __shared__ int4   sIdx[PTILE];
    __shared__ float4 sWt[PTILE];

    int tid = threadIdx.x;
    int pos0 = blockIdx.x * PTILE;         // 98 tiles
    int b = blockIdx.z;
    int po = (tid & 7) * 4;                // 4 consecutive positions
    int co = (tid >> 3) * 8;               // 8 consecutive couts

    float acc[8][4] = {};
    const float* xb = x + (size_t)b*CIN_*HW_;

    for (int kk = 0; kk < KK_; ++kk) {
        __syncthreads();                   // prev compute done before param overwrite
        if (tid < PTILE) {
            int e = (b*KK_ + kk)*HW_ + pos0 + tid;
            sIdx[tid] = pidx[e];
            sWt[tid]  = pwgt[e];
        }
        for (int cb = 0; cb < CIN_/CB; ++cb) {
            __syncthreads();               // params visible / prev compute done
            // stage sA: 32x256 f32 = 2048 float4, 8 per thread, coalesced
            {
                const float4* src = (const float4*)(Wt + (size_t)(kk*CIN_ + cb*CB)*COUT_);
                float4* dst = (float4*)(&sA[0][0]);
                #pragma unroll
                for (int j = 0; j < 8; ++j) dst[j*256 + tid] = src[j*256 + tid];
            }
            // stage sB: gather + bilinear blend; thread -> (ci = tid>>3, 4 pos)
            {
                int ci = tid >> 3;
                const float* xr = xb + (size_t)(cb*CB + ci)*HW_;
                int p0 = (tid & 7) * 4;
                #pragma unroll
                for (int j = 0; j < 4; ++j) {
                    int p = p0 + j;
                    int4   id = sIdx[p];
                    float4 wv = sWt[p];
                    float v = wv.x*xr[id.x] + wv.y*xr[id.y]
                            + wv.z*xr[id.z] + wv.w*xr[id.w];
                    sB[ci][p] = v;
                }
            }
            __syncthreads();
            #pragma unroll
            for (int k = 0; k < CB; ++k) {
                float av[8], bv[4];
                #pragma unroll
                for (int j = 0; j < 4; ++j) bv[j] = sB[k][po + j];
                #pragma unroll
                for (int i = 0; i < 8; ++i) av[i] = sA[k][co + i];
                #pragma unroll
                for (int i = 0; i < 8; ++i)
                    #pragma unroll
                    for (int j = 0; j < 4; ++j) acc[i][j] += av[i]*bv[j];
            }
        }
    }
    // epilogue: fp32 store
    #pragma unroll
    for (int i = 0; i < 8; ++i) {
        float* orow = out + (size_t)(b*COUT_ + co + i)*HW_ + pos0 + po;
        #pragma unroll
        for (int j = 0; j < 4; ++j) orow[j] = acc[i][j];
    }
}

// ---------------------------------------------------------------------------
extern "C" void kernel_launch(void* const* d_in, const int* in_sizes, int n_in,
                              void* d_out, int out_size, void* d_ws, size_t ws_size,
                              hipStream_t stream) {
    const float* x   = (const float*)d_in[0];
    const float* wgt = (const float*)d_in[1];
    const float* ow  = (const float*)d_in[2];
    const float* ob  = (const float*)d_in[3];
    float* out = (float*)d_out;

    char* ws = (char*)d_ws;
    // ws layout (16B-aligned): offs fp32 | Wt fp32 | pidx int4 | pwgt float4
    float*  offs = (float*)ws;                       // 225792 f -> 903168 B
    float*  Wt   = (float*)(ws + 903168);            // 589824 f -> 2359296 B
    int4*   pidx = (int4*) (ws + 3262464);           // 112896*16 B
    float4* pwgt = (float4*)(ws + 5068800);          // 112896*16 B  (end ~6.9MB)

    k_offset<<<dim3(B_N*18*HH_), 64, 0, stream>>>(x, ow, ob, offs);
    k_wt<<<dim3((COUT_*CIN_*KK_ + 255)/256), 256, 0, stream>>>(wgt, Wt);
    k_bilin<<<dim3((NPOS + 255)/256), 256, 0, stream>>>(offs, pidx, pwgt);
    k_main<<<dim3(98, 1, 4), 256, 0, stream>>>(x, Wt, pidx, pwgt, out);
}

// Round 4
// 391.045 us; speedup vs baseline: 1.7965x; 1.7965x over previous
//
#include <hip/hip_runtime.h>
#include <hip/hip_bf16.h>
#include <string.h>

// Problem constants
#define B_N   4
#define CIN_  256
#define HH_   56
#define WW_   56
#define COUT_ 256
#define KK_   9
#define HW_   3136              // 56*56
#define KDIM  2304              // CIN_*KK_  (k index = kk*256 + ci)
#define NDIM  12544             // B_N*HW_

typedef __attribute__((ext_vector_type(8))) short short8;   // 8 bf16 (4 VGPRs)
typedef __attribute__((ext_vector_type(4))) float float4v;  // MFMA accum

__device__ __forceinline__ short f2bf_bits(float v) {
    union { __hip_bfloat16 h; short s; } u;
    u.h = __float2bfloat16(v);
    return u.s;
}

// ---------------------------------------------------------------------------
// k_owt: transpose offset weights [18][256][9] -> owT[ci][c*9+kk] fp32
// so k_offset2's weight address is wave-uniform & contiguous per ci.
// ---------------------------------------------------------------------------
__global__ __launch_bounds__(256) void k_owt(const float* __restrict__ ow,
                                             float* __restrict__ owT) {
    int i = blockIdx.x*256 + threadIdx.x;        // i = ci*162 + c*9 + kk
    if (i >= 18*CIN_*KK_) return;
    int ci = i / 162; int r = i % 162;
    int c = r / 9;    int kk = r % 9;
    owT[i] = ow[(size_t)(c*CIN_ + ci)*9 + kk];
}

// ---------------------------------------------------------------------------
// k_prep: weight [Cout][Cin][9] fp32 -> At[cout][k=kk*256+ci] bf16
// (A matrix of the main GEMM, k-contiguous rows).
// ---------------------------------------------------------------------------
__global__ __launch_bounds__(256) void k_prep(const float* __restrict__ wgt,
                                              short* __restrict__ At) {
    int i = blockIdx.x*256 + threadIdx.x;        // i = o*2304 + kk*256 + ci
    if (i >= COUT_*KDIM) return;
    int o = i / KDIM; int r = i % KDIM;
    int kk = r >> 8;  int ci = r & 255;
    At[i] = f2bf_bits(wgt[(size_t)(o*CIN_ + ci)*9 + kk]);
}

// ---------------------------------------------------------------------------
// k_offset2: 3x3 offset conv. Block = (b,h), 256 threads = 4 waves.
// Wave q handles ci in [q*64, q*64+64); lane = w. Patch via shfl (zero-pad
// by masked loads/shuffles). All 18 channels accumulated per thread (x rows
// read once, reused 18x). LDS reduce over waves + bias.
// ---------------------------------------------------------------------------
__global__ __launch_bounds__(256) void k_offset2(const float* __restrict__ x,
                                                 const float* __restrict__ owT,
                                                 const float* __restrict__ ob,
                                                 float* __restrict__ offs) {
    __shared__ float red[4][18][64];             // 18 KB
    int t = threadIdx.x;
    int w = t & 63;  int q = t >> 6;
    int b = blockIdx.x / HH_, h = blockIdx.x % HH_;
    const float* xb = x + (size_t)b*CIN_*HW_;

    float acc[18];
    #pragma unroll
    for (int c = 0; c < 18; ++c) acc[c] = 0.f;

    for (int i = 0; i < 64; ++i) {
        int ci = q*64 + i;                       // wave-uniform
        const float* xp = xb + (size_t)ci*HW_;
        float v[3], patch[9];
        #pragma unroll
        for (int kh = 0; kh < 3; ++kh) {
            int yy = h - 1 + kh;
            v[kh] = (w < WW_ && yy >= 0 && yy < HH_) ? xp[yy*WW_ + w] : 0.f;
        }
        #pragma unroll
        for (int kh = 0; kh < 3; ++kh) {
            float c0 = v[kh];
            float l = __shfl_up(c0, 1);  if (w == 0) l = 0.f;
            float r = __shfl_down(c0, 1);          // lanes >=56 hold 0 -> col 56 pad ok
            patch[kh*3+0] = l; patch[kh*3+1] = c0; patch[kh*3+2] = r;
        }
        const float* wp = owT + (size_t)ci*162;  // wave-uniform address
        #pragma unroll
        for (int c = 0; c < 18; ++c) {
            float a = acc[c];
            #pragma unroll
            for (int kk = 0; kk < 9; ++kk) a += patch[kk]*wp[c*9+kk];
            acc[c] = a;
        }
    }
    #pragma unroll
    for (int c = 0; c < 18; ++c) red[q][c][w] = acc[c];
    __syncthreads();
    for (int o = t; o < 18*WW_; o += 256) {
        int c = o / WW_, w2 = o % WW_;
        float s = red[0][c][w2] + red[1][c][w2] + red[2][c][w2] + red[3][c][w2] + ob[c];
        offs[(size_t)(b*18 + c)*HW_ + h*WW_ + w2] = s;
    }
}

// ---------------------------------------------------------------------------
// k_sample: build S[n][k] bf16 (n = b*3136+pos, k = kk*256+ci).
// Block = (b, kk, 64-pos strip). First 64 threads compute bilinear params
// (corner idx + weights, zero weight for OOB) into LDS; then all threads
// gather-blend 8 ci per pass (8 passes), one 16B store each.
// ---------------------------------------------------------------------------
__global__ __launch_bounds__(256) void k_sample(const float* __restrict__ x,
                                                const float* __restrict__ offs,
                                                short* __restrict__ S) {
    __shared__ int4   sI[64];
    __shared__ float4 sW[64];
    int t = threadIdx.x;
    int b = blockIdx.z, kk = blockIdx.y;
    int pos0 = blockIdx.x * 64;

    if (t < 64) {
        int pos = pos0 + t;
        int h = pos / WW_, w = pos % WW_;
        float dy = offs[(size_t)(b*18 + 2*kk    )*HW_ + pos];
        float dx = offs[(size_t)(b*18 + 2*kk + 1)*HW_ + pos];
        float py = (float)(h - 1 + kk/3) + dy;
        float px = (float)(w - 1 + kk%3) + dx;
        float y0f = floorf(py), x0f = floorf(px);
        int y0 = (int)y0f, x0 = (int)x0f;
        float ty = py - y0f, tx = px - x0f;
        int   ys[2] = {y0, y0 + 1},   xs[2] = {x0, x0 + 1};
        float wy[2] = {1.f - ty, ty}, wx[2] = {1.f - tx, tx};
        int idx[4]; float wt[4];
        #pragma unroll
        for (int jy = 0; jy < 2; ++jy)
            #pragma unroll
            for (int jx = 0; jx < 2; ++jx) {
                int j = jy*2 + jx;
                int yy = ys[jy], xx = xs[jx];
                bool vd = (yy >= 0) && (yy < HH_) && (xx >= 0) && (xx < WW_);
                int yc = min(max(yy, 0), HH_-1);
                int xc = min(max(xx, 0), WW_-1);
                idx[j] = yc*WW_ + xc;
                wt[j]  = vd ? wy[jy]*wx[jx] : 0.f;
            }
        sI[t] = make_int4(idx[0], idx[1], idx[2], idx[3]);
        sW[t] = make_float4(wt[0], wt[1], wt[2], wt[3]);
    }
    __syncthreads();

    int lane = t & 63;  int g = t >> 6;
    int4   id = sI[lane];
    float4 wv = sW[lane];
    const float* xb = x + (size_t)b*CIN_*HW_;
    size_t nrow = (size_t)(b*HW_ + pos0 + lane)*KDIM + kk*256;

    for (int cc = 0; cc < 8; ++cc) {
        int ci0 = cc*32 + g*8;
        short8 pack;
        #pragma unroll
        for (int j = 0; j < 8; ++j) {
            const float* xr = xb + (size_t)(ci0 + j)*HW_;
            float v = wv.x*xr[id.x] + wv.y*xr[id.y]
                    + wv.z*xr[id.z] + wv.w*xr[id.w];
            pack[j] = f2bf_bits(v);
        }
        *(short8*)(S + nrow + ci0) = pack;       // 16B store, L2 merges lines
    }
}

// ---------------------------------------------------------------------------
// k_gemm: out[b][cout][pos] = sum_k At[cout][k] * S[n][k], bf16 MFMA
// 16x16x32, fp32 accum. BM=BN=64, BK=32, 256 threads = 4 waves (2x2),
// each wave computes 32x32 (2x2 MFMA tiles). Grid: x = N/64 = 196, y = 4.
// LDS rows padded to 40 halfwords (80B) to break b128 bank conflicts.
// ---------------------------------------------------------------------------
__global__ __launch_bounds__(256) void k_gemm(const short* __restrict__ At,
                                              const short* __restrict__ S,
                                              float* __restrict__ out) {
    __shared__ short sA[64][40];
    __shared__ short sB[64][40];
    int t = threadIdx.x;
    int m0 = blockIdx.y * 64;
    int n0 = blockIdx.x * 64;

    int row = t >> 2;            // 0..63  (staging row)
    int kof = (t & 3) * 8;       // 0,8,16,24

    int wv = t >> 6;             // wave id
    int wm = (wv >> 1) * 32;     // wave m offset
    int wn = (wv & 1) * 32;      // wave n offset
    int lane = t & 63;
    int lm = lane & 15;          // m/n index within 16
    int qd = lane >> 4;          // quad -> k-chunk (A/B), row group (C/D)

    float4v acc[2][2];
    #pragma unroll
    for (int i = 0; i < 2; ++i)
        #pragma unroll
        for (int j = 0; j < 2; ++j) acc[i][j] = (float4v)(0.f);

    const short* gA = At + (size_t)(m0 + row)*KDIM + kof;
    const short* gB = S  + (size_t)(n0 + row)*KDIM + kof;

    for (int kt = 0; kt < KDIM; kt += 32) {
        __syncthreads();
        *(short8*)&sA[row][kof] = *(const short8*)(gA + kt);
        *(short8*)&sB[row][kof] = *(const short8*)(gB + kt);
        __syncthreads();
        short8 af[2], bf[2];
        #pragma unroll
        for (int i = 0; i < 2; ++i) {
            af[i] = *(short8*)&sA[wm + i*16 + lm][qd*8];
            bf[i] = *(short8*)&sB[wn + i*16 + lm][qd*8];
        }
        #pragma unroll
        for (int i = 0; i < 2; ++i)
            #pragma unroll
            for (int j = 0; j < 2; ++j)
                acc[i][j] = __builtin_amdgcn_mfma_f32_16x16x32_bf16(
                                af[i], bf[j], acc[i][j], 0, 0, 0);
    }

    // epilogue: C/D layout col=lane&15 (n), row=qd*4+r (m)
    int b    = blockIdx.x / 49;
    int posb = (blockIdx.x % 49) * 64;
    #pragma unroll
    for (int i = 0; i < 2; ++i)
        #pragma unroll
        for (int j = 0; j < 2; ++j) {
            int col = posb + wn + j*16 + lm;
            #pragma unroll
            for (int r = 0; r < 4; ++r) {
                int m = m0 + wm + i*16 + qd*4 + r;
                out[((size_t)b*COUT_ + m)*HW_ + col] = acc[i][j][r];
            }
        }
}

// ---------------------------------------------------------------------------
extern "C" void kernel_launch(void* const* d_in, const int* in_sizes, int n_in,
                              void* d_out, int out_size, void* d_ws, size_t ws_size,
                              hipStream_t stream) {
    const float* x   = (const float*)d_in[0];
    const float* wgt = (const float*)d_in[1];
    const float* ow  = (const float*)d_in[2];
    const float* ob  = (const float*)d_in[3];
    float* out = (float*)d_out;

    char* ws = (char*)d_ws;
    // ws layout (16B aligned): offs fp32 | At bf16 | owT fp32 | S bf16
    float* offs = (float*)ws;                        // 225792*4  =   903168
    short* At   = (short*)(ws + 903168);             // 589824*2  =  1179648
    float* owT  = (float*)(ws + 2082816);            // 41472*4   =   165888
    short* S    = (short*)(ws + 2248704);            // 28901376*2 = 57802752
                                                     // total ~60.1 MB

    k_owt    <<<dim3((18*CIN_*KK_ + 255)/256), 256, 0, stream>>>(ow, owT);
    k_prep   <<<dim3((COUT_*KDIM + 255)/256),  256, 0, stream>>>(wgt, At);
    k_offset2<<<dim3(B_N*HH_),                 256, 0, stream>>>(x, owT, ob, offs);
    k_sample <<<dim3(49, 9, 4),                256, 0, stream>>>(x, offs, S);
    k_gemm   <<<dim3(196, 4),                  256, 0, stream>>>(At, S, out);
}